// Round 7
// baseline (252.616 us; speedup 1.0000x reference)
//
#include <hip/hip_runtime.h>
#include <math.h>

#define K_DIM 256
#define BM 128      // db rows per block
#define BN 256      // query cols per block
#define BK 32       // K per double-buffer step (2 k16-chunks); 8 steps

typedef unsigned long long u64;
typedef __attribute__((ext_vector_type(8))) short bf16x8;   // MFMA A/B frag (4 VGPR)
typedef __attribute__((ext_vector_type(16))) float f32x16;  // 32x32 MFMA C/D frag

// Monotone map fp32 -> u32 so unsigned compare == float compare.
__device__ __forceinline__ u64 packKey(float v, unsigned idx) {
    unsigned u = __float_as_uint(v);
    u = (u & 0x80000000u) ? ~u : (u | 0x80000000u);
    return ((u64)u << 32) | idx;
}
__device__ __forceinline__ float unpackVal(u64 k) {
    unsigned u = (unsigned)(k >> 32);
    u = (u & 0x80000000u) ? (u ^ 0x80000000u) : ~u;
    return __uint_as_float(u);
}
__device__ __forceinline__ u64 shfl_xor_u64(u64 x, int m) {
    unsigned lo = (unsigned)x, hi = (unsigned)(x >> 32);
    lo = __shfl_xor(lo, m, 64);
    hi = __shfl_xor(hi, m, 64);
    return ((u64)hi << 32) | lo;
}

__device__ __forceinline__ unsigned short f2bf(float x) {   // RNE fp32->bf16
    unsigned u = __float_as_uint(x);
    return (unsigned short)((u + 0x7FFFu + ((u >> 16) & 1u)) >> 16);
}
__device__ __forceinline__ float bf2f(unsigned short b) {
    return __uint_as_float((unsigned)b << 16);
}

// Packed fragment layout for 32x32x16 MFMA (per tensor):
// cell(c,t) = 1 KB, c = k-chunk (k = 16c + 8*(lane>>5) + j), t = row/32,
// lane holds row 32t + (lane&31), 8 consecutive k (16 B). A and B operand
// layouts are identical for 32x32x16, so one packing serves both sides.

// One wave per row: quantize fp32->bf16 into PACKED layout, compute the
// norm of the QUANTIZED vector, init min-key arrays + output.
__global__ void convert_kernel(const float* __restrict__ real, const float* __restrict__ gen,
                               short* __restrict__ realP, short* __restrict__ genP,
                               float* __restrict__ rn, float* __restrict__ gn,
                               u64* __restrict__ realKey, u64* __restrict__ genKey,
                               float* __restrict__ out, int N, int M) {
    int wv = (blockIdx.x * blockDim.x + threadIdx.x) >> 6;
    int lane = threadIdx.x & 63;
    if (wv >= N + M) return;
    const float* src;
    short* dstP;
    int r, NT;
    if (wv < N) { src = real + (size_t)wv * K_DIM; dstP = realP; r = wv; NT = N >> 5; }
    else        { src = gen + (size_t)(wv - N) * K_DIM; dstP = genP; r = wv - N; NT = M >> 5; }
    float4 v = ((const float4*)src)[lane];   // k = 4*lane .. 4*lane+3
    ushort4 b;
    b.x = f2bf(v.x); b.y = f2bf(v.y); b.z = f2bf(v.z); b.w = f2bf(v.w);
    float qx = bf2f(b.x), qy = bf2f(b.y), qz = bf2f(b.z), qw = bf2f(b.w);
    float s = qx * qx + qy * qy + qz * qz + qw * qw;
    // dest: c = k/16 = lane>>2, khi = (k>>3)&1 = (lane>>1)&1, j0 = (lane&1)*4
    int c = lane >> 2;
    int lane_p = (r & 31) + (((lane >> 1) & 1) << 5);
    size_t sidx = (((size_t)c * NT + (r >> 5)) * 64 + lane_p) * 8 + (lane & 1) * 4;
    *(ushort4*)(dstP + sidx) = b;
    #pragma unroll
    for (int off = 32; off > 0; off >>= 1) s += __shfl_down(s, off, 64);
    if (lane == 0) {
        if (wv < N) { rn[wv] = s; realKey[wv] = ~0ull; }
        else        { gn[wv - N] = s; genKey[wv - N] = ~0ull; }
        if (wv == 0) out[0] = 0.f;
    }
}

// Fused bf16-MFMA GEMM + column-min(+argmin). blockIdx.z: 0 = real queries
// (diagonal excluded), 1 = gen queries. Min is over db rows (real).
//
// STAGED A+B, 2 BLOCKS/CU. The free-run structure (R0/R1/R6) plateaus at
// ~930 TF (the documented stream-one-operand ceiling); R5's staged 256^2
// version hit the 2-phase convoy (1 block/CU -> every barrier drains the
// whole CU, 729 TF). This version keeps R5's proven counted-vmcnt dbuf
// schedule but resizes to 128x256 tile, BK=32: staging 24 KB/step,
// dbuf 48 KB + 2 KB reduce = 50 KB LDS -> TWO independent 512-thread
// blocks per CU. When one block sits at a barrier, the other's waves
// keep the MFMA/LDS pipes busy - the cross-block overlap R5 lacked.
// 8 waves (2wi x 4wj), wave tile 64x64, acc 64 AGPR + ~35 arch: no
// spill class. Per K-step/wave: 3 global_load_lds (next step, counted
// vmcnt(3) stays in flight across the barrier), 8 ds_read_b128, 8 MFMA.
// Full K=256 accumulated -> single epilogue (R1 math, mi->rc).
__global__ __launch_bounds__(512, 4) void nn_kernel(
    const short* __restrict__ realP, const short* __restrict__ genP,
    const float* __restrict__ rn,
    u64* __restrict__ realKey, u64* __restrict__ genKey,
    int N, int M) {

    const bool isReal = (blockIdx.z == 0);
    const short* __restrict__ qP = isReal ? realP : genP;
    u64* outKey = isReal ? realKey : genKey;

    const int j0 = blockIdx.x * BN;
    const int r0 = blockIdx.y * BM;
    const int NTA = N >> 5;
    const int NTB = (isReal ? N : M) >> 5;

    // LDS: A dbuf 2x8 KB @0, B dbuf 2x16 KB @16K -> 48 KB; red 2 KB.
    __shared__ __attribute__((aligned(16))) char smem[49152];
    __shared__ u64 red[BN];

    const int tid = threadIdx.x;
    const int lane = tid & 63;
    const int w = tid >> 6;            // 0..7
    const int wi = w >> 2;             // wave's 64-row block: 0..1
    const int wj = w & 3;              // wave's 64-col block: 0..3
    const int hi = lane >> 5;          // k-half / row-half selector
    const int col = lane & 31;
    const int cd = col - 4 * hi;       // diag test: diag iff cd == e + 8g
    const int jBase = j0 + wj * 64;

    // Stage K-step ks into buf: 24 cells of 1 KB (A: cid=c*4+t, 8 cells;
    // B: bc=c*8+t, 16 cells). Wave w loads cells 3w..3w+2. LDS dest is
    // the uniform cell base (HW scatters lane*16); global src is per-lane.
    auto stage = [&](int ks, int buf) {
        #pragma unroll
        for (int p = 0; p < 3; ++p) {
            const int cid = w * 3 + p;                 // 0..23
            if (cid < 8) {                              // A cell
                const int c = cid >> 2, t = cid & 3;
                const char* src = (const char*)realP +
                    (((size_t)(ks * 2 + c) * NTA) + (r0 >> 5) + t) * 1024 +
                    (size_t)lane * 16;
                __builtin_amdgcn_global_load_lds(
                    (const __attribute__((address_space(1))) void*)src,
                    (__attribute__((address_space(3))) void*)(smem + buf * 8192 + cid * 1024),
                    16, 0, 0);
            } else {                                    // B cell
                const int bc = cid - 8;
                const int c = bc >> 3, t = bc & 7;
                const char* src = (const char*)qP +
                    (((size_t)(ks * 2 + c) * NTB) + (j0 >> 5) + t) * 1024 +
                    (size_t)lane * 16;
                __builtin_amdgcn_global_load_lds(
                    (const __attribute__((address_space(1))) void*)src,
                    (__attribute__((address_space(3))) void*)(smem + 16384 + buf * 16384 + bc * 1024),
                    16, 0, 0);
            }
        }
    };

    f32x16 acc[2][2];
    #pragma unroll
    for (int rc = 0; rc < 2; ++rc)
        #pragma unroll
        for (int ni = 0; ni < 2; ++ni)
            acc[rc][ni] = (f32x16){0.f,0.f,0.f,0.f,0.f,0.f,0.f,0.f,
                                   0.f,0.f,0.f,0.f,0.f,0.f,0.f,0.f};

    stage(0, 0);                       // prologue
    if (tid < BN) red[tid] = ~0ull;

    #pragma unroll
    for (int ks = 0; ks < 8; ++ks) {
        if (ks < 7) {
            stage(ks + 1, (ks + 1) & 1);               // next step in flight
            asm volatile("s_waitcnt vmcnt(3)" ::: "memory");   // step ks landed
        } else {
            asm volatile("s_waitcnt vmcnt(0)" ::: "memory");
        }
        __builtin_amdgcn_s_barrier();                  // buf[ks&1] ready
        __builtin_amdgcn_sched_barrier(0);
        {
            const char* Ax = smem + (ks & 1) * 8192 + (wi * 2) * 1024 + (size_t)lane * 16;
            const char* Bx = smem + 16384 + (ks & 1) * 16384 + (wj * 2) * 1024 + (size_t)lane * 16;
            #pragma unroll
            for (int c = 0; c < 2; ++c) {
                bf16x8 a0 = *(const bf16x8*)(Ax + c * 4096);
                bf16x8 a1 = *(const bf16x8*)(Ax + c * 4096 + 1024);
                bf16x8 b0 = *(const bf16x8*)(Bx + c * 8192);
                bf16x8 b1 = *(const bf16x8*)(Bx + c * 8192 + 1024);
                __builtin_amdgcn_s_setprio(1);
                acc[0][0] = __builtin_amdgcn_mfma_f32_32x32x16_bf16(a0, b0, acc[0][0], 0, 0, 0);
                acc[0][1] = __builtin_amdgcn_mfma_f32_32x32x16_bf16(a0, b1, acc[0][1], 0, 0, 0);
                acc[1][0] = __builtin_amdgcn_mfma_f32_32x32x16_bf16(a1, b0, acc[1][0], 0, 0, 0);
                acc[1][1] = __builtin_amdgcn_mfma_f32_32x32x16_bf16(a1, b1, acc[1][1], 0, 0, 0);
                __builtin_amdgcn_s_setprio(0);
            }
        }
        asm volatile("s_waitcnt lgkmcnt(0)" ::: "memory");  // reads of buf done
        __builtin_amdgcn_s_barrier();                  // safe to overwrite buf
        __builtin_amdgcn_sched_barrier(0);
    }

    // ---- Epilogue (once, full K accumulated): v = rn[i] - 2*dot
    // (qn[j] + sqrt deferred; monotone per column).
    // C/D layout (32x32): col = lane&31, row = e + 8g + 4hi (r = 4g+e). ----
    const int Rt = r0 + wi * 64;
    float minv[2];
    int mini[2];
    minv[0] = minv[1] = 3.4e38f;
    mini[0] = mini[1] = 0;

    if (isReal) {
        // Value-only min; diagonal handled by wave-uniform block check.
        #pragma unroll
        for (int rc = 0; rc < 2; ++rc) {
            const bool diag0 = (Rt + rc * 32) == (jBase);
            const bool diag1 = (Rt + rc * 32) == (jBase + 32);
            #pragma unroll
            for (int g = 0; g < 4; ++g) {
                float4 rnv = *(const float4*)(rn + Rt + rc * 32 + 4 * hi + 8 * g);
                #pragma unroll
                for (int e = 0; e < 4; ++e) {
                    float v0 = (&rnv.x)[e] - 2.f * acc[rc][0][4 * g + e];
                    float v1 = (&rnv.x)[e] - 2.f * acc[rc][1][4 * g + e];
                    if (diag0 && cd == e + 8 * g) v0 = 3.4e38f;
                    if (diag1 && cd == e + 8 * g) v1 = 3.4e38f;
                    minv[0] = fminf(minv[0], v0);
                    minv[1] = fminf(minv[1], v1);
                }
            }
        }
    } else {
        // Argmin via in-tile code; resolve to global row once.
        float tv[2] = {3.4e38f, 3.4e38f};
        int tc[2] = {0, 0};
        #pragma unroll
        for (int rc = 0; rc < 2; ++rc)
            #pragma unroll
            for (int g = 0; g < 4; ++g) {
                float4 rnv = *(const float4*)(rn + Rt + rc * 32 + 4 * hi + 8 * g);
                #pragma unroll
                for (int e = 0; e < 4; ++e) {
                    float v0 = (&rnv.x)[e] - 2.f * acc[rc][0][4 * g + e];
                    float v1 = (&rnv.x)[e] - 2.f * acc[rc][1][4 * g + e];
                    if (v0 < tv[0]) { tv[0] = v0; tc[0] = rc * 16 + g * 4 + e; }
                    if (v1 < tv[1]) { tv[1] = v1; tc[1] = rc * 16 + g * 4 + e; }
                }
            }
        #pragma unroll
        for (int ni = 0; ni < 2; ++ni) {
            int ig = Rt + ((tc[ni] >> 4) << 5) + (((tc[ni] >> 2) & 3) << 3)
                     + (tc[ni] & 3) + (hi << 2);
            if (tv[ni] < minv[ni]) { minv[ni] = tv[ni]; mini[ni] = ig; }
        }
    }

    // Block reduction: lanes +-32 share a column; LDS atomic merge of the
    // wi waves, one global atomic per column.
    #pragma unroll
    for (int ni = 0; ni < 2; ++ni) {
        u64 k = packKey(minv[ni], (unsigned)mini[ni]);
        u64 o = shfl_xor_u64(k, 32); if (o < k) k = o;
        if (hi == 0) atomicMin(&red[wj * 64 + ni * 32 + col], k);
    }
    __syncthreads();
    if (tid < BN) atomicMin(&outKey[j0 + tid], red[tid]);
}

__global__ void finalize_kernel(const u64* __restrict__ realKey, const u64* __restrict__ genKey,
                                const float* __restrict__ rn, const float* __restrict__ gn,
                                float* __restrict__ out, int M) {
    int j = blockIdx.x * blockDim.x + threadIdx.x;
    float a = 0.f;
    if (j < M) {
        u64 gk = genKey[j];
        float mg = unpackVal(gk);
        int idx = (int)(gk & 0xFFFFFFFFu);
        float d1 = sqrtf(fmaxf(mg + gn[j], 0.f));
        u64 rk = realKey[idx];
        float d2 = sqrtf(fmaxf(unpackVal(rk) + rn[idx], 0.f));
        float z = (d2 - d1) * 10.f;   // / TEMP
        a = 1.f / (1.f + expf(-z));
    }
    #pragma unroll
    for (int off = 32; off > 0; off >>= 1) a += __shfl_down(a, off, 64);
    __shared__ float sred[4];
    int lane = threadIdx.x & 63, wv = threadIdx.x >> 6;
    if (lane == 0) sred[wv] = a;
    __syncthreads();
    if (threadIdx.x == 0) {
        float s = sred[0] + sred[1] + sred[2] + sred[3];
        atomicAdd(out, s * (-100.f / (float)M));
    }
}

extern "C" void kernel_launch(void* const* d_in, const int* in_sizes, int n_in,
                              void* d_out, int out_size, void* d_ws, size_t ws_size,
                              hipStream_t stream) {
    const float* real = (const float*)d_in[0];
    const float* gen  = (const float*)d_in[1];
    float* out = (float*)d_out;
    int N = in_sizes[0] / K_DIM;
    int M = in_sizes[1] / K_DIM;

    // Workspace layout (~12.9 MB total):
    u64* realKey = (u64*)d_ws;
    u64* genKey  = realKey + N;
    float* rn = (float*)(genKey + M);
    float* gn = rn + N;
    short* realP = (short*)(gn + M);
    short* genP  = realP + (size_t)N * K_DIM;

    int mx = (N > M ? N : M);
    convert_kernel<<<(N + M + 3) / 4, 256, 0, stream>>>(real, gen, realP, genP, rn, gn,
                                                        realKey, genKey, out, N, M);
    dim3 g((mx + BN - 1) / BN, (N + BM - 1) / BM, 2);
    nn_kernel<<<g, 512, 0, stream>>>(realP, genP, rn, realKey, genKey, N, M);
    finalize_kernel<<<(M + 255) / 256, 256, 0, stream>>>(realKey, genKey, rn, gn, out, M);
}